// Round 11
// baseline (159.740 us; speedup 1.0000x reference)
//
#include <hip/hip_runtime.h>
#include <hip/hip_bf16.h>

typedef unsigned short ushort_t;
typedef __attribute__((ext_vector_type(8))) short bf16x8;
typedef __attribute__((ext_vector_type(4))) float f32x4;

__device__ __forceinline__ ushort_t f2bf(float f) {
    union { float f; unsigned u; } v; v.f = f;
    unsigned r = v.u + 0x7FFF + ((v.u >> 16) & 1);
    return (ushort_t)(r >> 16);
}
__device__ __forceinline__ float bfl(ushort_t u) {
    union { unsigned u; float f; } v; v.u = (unsigned)u << 16; return v.f;
}
__device__ __forceinline__ bf16x8 ld8(const ushort_t* p) { return *(const bf16x8*)p; }

__device__ __forceinline__ unsigned cvt2(float x, float y) {
    __hip_bfloat162 h = __float22bfloat162_rn(make_float2(x, y));
    unsigned r; __builtin_memcpy(&r, &h, 4); return r;
}
__device__ __forceinline__ bf16x8 pack8f(float4 a, float4 b) {
    union { unsigned u[4]; bf16x8 v; } o;
    o.u[0] = cvt2(a.x, a.y); o.u[1] = cvt2(a.z, a.w);
    o.u[2] = cvt2(b.x, b.y); o.u[3] = cvt2(b.z, b.w);
    return o.v;
}

// async global->LDS, 16B per lane; LDS dest = wave-uniform base + lane*16
__device__ __forceinline__ void gload_lds16(const ushort_t* g, ushort_t* l) {
    __builtin_amdgcn_global_load_lds(
        (const __attribute__((address_space(1))) void*)g,
        (__attribute__((address_space(3))) void*)l, 16, 0, 0);
}

// ---------------------------------------------------------------------------
// W-only cast: Wq|Wk|Wv|Wo f32 -> Wb bf16 (4 x 2^18). 512 blocks (~1.5 us).
// Activations are consumed as f32 directly by proj (hybrid staging).
// ---------------------------------------------------------------------------
__global__ __launch_bounds__(256)
void cast_w_kernel(const float* __restrict__ Wq, const float* __restrict__ Wk,
                   const float* __restrict__ Wv, const float* __restrict__ Wo,
                   ushort_t* __restrict__ Wb)
{
    const unsigned i8 = (blockIdx.x * 256u + threadIdx.x) * 8u;   // < 2^20
    unsigned a = i8 >> 18, off = i8 & ((1u << 18) - 1);
    const float* src = (a == 0 ? Wq : a == 1 ? Wk : a == 2 ? Wv : Wo) + off;
    *(bf16x8*)(Wb + i8) = pack8f(*(const float4*)src, *(const float4*)(src + 4));
}

// ---------------------------------------------------------------------------
// Fused QKV projection v12 (hybrid staging, race-fixed): 64x128 tile,
// grid (4,64,3) = 768 = 3 x 256 blocks, 48 KB LDS double-buffered.
//  - A: f32 global -> regs -> pack8f -> swizzled ds_write into NEXT buffer.
//    RACE FIX vs v11: ds_write is lgkm-tracked; raw s_barrier does NOT
//    drain lgkmcnt, so an explicit s_waitcnt lgkmcnt(0) now precedes the
//    barrier (the discipline __syncthreads() normally provides).
//  - W: bf16 (cast_w), global_load_lds DMA with pre-swizzled source
//    (vmcnt-tracked, drained by the existing vmcnt(0)).
// z=0: Q*C1; z=1: K; z=2: V^T rho-permuted via LDS-transpose epilogue.
// ---------------------------------------------------------------------------
__global__ __launch_bounds__(256, 3)
void proj_qkv_kernel(const float* __restrict__ Qe, const float* __restrict__ Ke,
                     const float* __restrict__ x,  const ushort_t* __restrict__ Wb,
                     const float* __restrict__ bq, const float* __restrict__ bk,
                     const float* __restrict__ bv,
                     ushort_t* __restrict__ Qo, ushort_t* __restrict__ Ko,
                     ushort_t* __restrict__ Vt)
{
    __shared__ ushort_t smem[2 * 12288];   // 48 KB: [buf][A 64x64 | W 128x64]

    const int z = blockIdx.z;
    const float* Af = (z == 0) ? Qe : (z == 1) ? Ke : x;     // f32 activations
    const ushort_t* W = Wb + ((size_t)z << 18);
    const float* bias = (z == 0) ? bq : (z == 1) ? bk : bv;

    const int m0 = blockIdx.y * 64, n0 = blockIdx.x * 128;
    const int t = threadIdx.x;
    const int lane = t & 63, wave = t >> 6;
    const int wm = (wave & 1) * 32, wn = (wave >> 1) * 64;
    const int fr = lane & 15, quad = lane >> 4;
    const int fr7 = fr & 7;

    // A reg-staging geometry: thread covers row t>>2, 16 f32 at col (t&3)*16.
    const int ar = t >> 2;
    const float* ags = Af + (size_t)(m0 + ar) * 512 + (t & 3) * 16;
    const int c0 = (t & 3) * 2;                       // first 8-elem chunk idx
    const int awo0 = ar * 64 + (((c0    ) ^ (ar & 7)) << 3);
    const int awo1 = ar * 64 + (((c0 + 1) ^ (ar & 7)) << 3);

    // W DMA: wave covers rows wave*32 + i*8 + (lane>>3), i=0..3
    const int wrl = wave * 32 + (lane >> 3);
    const ushort_t* wg = W + (size_t)(n0 + wrl) * 512 + (((lane & 7) ^ (wrl & 7)) << 3);
    const int dbW = 4096 + wave * 32 * 64;

    f32x4 acc[2][4] = {};
    float4 fa[4];

    // prologue: A(tile0) via regs + W(tile0) via DMA into buf 0
#pragma unroll
    for (int j = 0; j < 4; ++j) fa[j] = *(const float4*)(ags + j * 4);
#pragma unroll
    for (int i = 0; i < 4; ++i)
        gload_lds16(wg + (size_t)(i * 8) * 512, smem + dbW + i * 512);
    asm volatile("s_waitcnt vmcnt(0)" ::: "memory");
    *(bf16x8*)(smem + awo0) = pack8f(fa[0], fa[1]);
    *(bf16x8*)(smem + awo1) = pack8f(fa[2], fa[3]);
    __syncthreads();        // full waitcnt drain + barrier (safe)

    for (int kk = 0; kk < 8; ++kk) {
        ushort_t* cur = smem + (kk & 1) * 12288;
        ushort_t* nxt = smem + ((kk & 1) ^ 1) * 12288;
        if (kk < 7) {
            int ko = (kk + 1) * 64;
#pragma unroll
            for (int j = 0; j < 4; ++j) fa[j] = *(const float4*)(ags + ko + j * 4);
#pragma unroll
            for (int i = 0; i < 4; ++i)
                gload_lds16(wg + ko + (size_t)(i * 8) * 512, nxt + dbW + i * 512);
        }

#pragma unroll
        for (int ks = 0; ks < 2; ++ks) {
            bf16x8 af[2], bfr[4];
#pragma unroll
            for (int mt = 0; mt < 2; ++mt)
                af[mt] = ld8(cur + (wm + mt * 16 + fr) * 64 + (((ks * 4 + quad) ^ fr7) << 3));
#pragma unroll
            for (int nt = 0; nt < 4; ++nt)
                bfr[nt] = ld8(cur + 4096 + (wn + nt * 16 + fr) * 64 + (((ks * 4 + quad) ^ fr7) << 3));
#pragma unroll
            for (int mt = 0; mt < 2; ++mt)
#pragma unroll
                for (int nt = 0; nt < 4; ++nt)
                    acc[mt][nt] = __builtin_amdgcn_mfma_f32_16x16x32_bf16(
                        af[mt], bfr[nt], acc[mt][nt], 0, 0, 0);
        }
        asm volatile("s_waitcnt vmcnt(0)" ::: "memory");
        if (kk < 7) {     // A(nxt) pack+write: nxt's readers finished last barrier
            *(bf16x8*)(nxt + awo0) = pack8f(fa[0], fa[1]);
            *(bf16x8*)(nxt + awo1) = pack8f(fa[2], fa[3]);
        }
        // RACE FIX: drain LDS queue so the ds_writes are visible to all
        // waves after the barrier (raw s_barrier does not drain lgkmcnt).
        asm volatile("s_waitcnt lgkmcnt(0)" ::: "memory");
        __builtin_amdgcn_s_barrier();
        __builtin_amdgcn_sched_barrier(0);
    }

    const float C1 = 0.125f * 1.44269504088896340736f;
    if (z != 2) {
        ushort_t* dst = (z == 0) ? Qo : Ko;
#pragma unroll
        for (int nt = 0; nt < 4; ++nt) {
            int n = n0 + wn + nt * 16 + fr;
            float bb = bias[n];
#pragma unroll
            for (int mt = 0; mt < 2; ++mt) {
                int mb = m0 + wm + mt * 16 + quad * 4;
                if (z == 0) {
#pragma unroll
                    for (int r = 0; r < 4; ++r)
                        dst[(size_t)(mb + r) * 512 + n] = f2bf((acc[mt][nt][r] + bb) * C1);
                } else {
#pragma unroll
                    for (int r = 0; r < 4; ++r)
                        dst[(size_t)(mb + r) * 512 + n] = f2bf(acc[mt][nt][r] + bb);
                }
            }
        }
    } else {
        // V^T epilogue: rho-scatter (local 64-token form) then b128 stores.
        ushort_t* lT = smem;              // [nl 0..127][sg 0..63], stride 72
#pragma unroll
        for (int nt = 0; nt < 4; ++nt) {
            int nl = wn + nt * 16 + fr;
            float bb = bias[n0 + nl];
#pragma unroll
            for (int mt = 0; mt < 2; ++mt) {
                int tm = wm + mt * 16 + quad * 4;
#pragma unroll
                for (int r = 0; r < 4; ++r) {
                    int tl = tm + r;     // 0..63 local token
                    int sg = (tl & 32) + ((tl & 12) << 1) + ((tl >> 4 & 1) << 2) + (tl & 3);
                    lT[nl * 72 + sg] = f2bf(acc[mt][nt][r] + bb);
                }
            }
        }
        __syncthreads();
        const int bidx = m0 >> 11, m0t = m0 & 2047;
#pragma unroll
        for (int i = 0; i < 4; ++i) {
            int s = i * 256 + t;
            int row = s >> 3, c = s & 7;     // row 0..127, chunk 0..7
            int n = n0 + row;
            int h = n >> 6, d = n & 63;
            bf16x8 v = ld8(lT + row * 72 + c * 8);
            *(bf16x8*)(Vt + ((size_t)((bidx * 8 + h) * 64 + d)) * 2048 + m0t + c * 8) = v;
        }
    }
}

// ---------------------------------------------------------------------------
// Fused O-projection: A = bf16((O0+O1) * 1/(l0+l1)) from bf16 partials;
// W pre-cast to bf16 (cast_w). 64x64 tile, grid (8,64), BK=64 (h == kk).
// ---------------------------------------------------------------------------
__global__ __launch_bounds__(256, 2)
void gemm_o_kernel(const ushort_t* __restrict__ Oh, const float* __restrict__ Lsum,
                   const ushort_t* __restrict__ W, const float* __restrict__ bias,
                   float* __restrict__ dst)
{
    __shared__ ushort_t lA[64 * 72];
    __shared__ ushort_t lB[64 * 72];
    const int m0 = blockIdx.y * 64, n0 = blockIdx.x * 64;
    const int t = threadIdx.x;
    const int lane = t & 63, wave = t >> 6;
    const int wm = (wave & 1) * 32, wn = (wave >> 1) * 32;
    const int fr = lane & 15, quad = lane >> 4;
    const int bq_ = m0 >> 11, qq0 = m0 & 2047;

    f32x4 acc[2][2] = {};
    bf16x8 va0[2], va1[2], vw[2];
    float l0[2], l1[2];

#pragma unroll
    for (int i = 0; i < 2; ++i) {
        int s = i * 256 + t;
        int r = s >> 3, jp = s & 7;
        va0[i] = ld8(Oh + (size_t)(m0 + r) * 512 + jp * 8);
        va1[i] = ld8(Oh + (size_t)(m0 + r + 4096) * 512 + jp * 8);
        l0[i] = Lsum[(bq_ * 8 + 0) * 2048 + qq0 + r];
        l1[i] = Lsum[((2 + bq_) * 8 + 0) * 2048 + qq0 + r];
        vw[i] = ld8(W + (size_t)(n0 + r) * 512 + jp * 8);
    }

    for (int kk = 0; kk < 8; ++kk) {
        if (kk) __syncthreads();
#pragma unroll
        for (int i = 0; i < 2; ++i) {
            int s = i * 256 + t;
            int r = s >> 3, jp = s & 7;
            float inv = 1.f / (l0[i] + l1[i]);
            union { bf16x8 v; ushort_t s8[8]; } a0, a1;
            a0.v = va0[i]; a1.v = va1[i];
            union { unsigned u[4]; bf16x8 v; } o;
#pragma unroll
            for (int j = 0; j < 4; ++j)
                o.u[j] = cvt2((bfl(a0.s8[2 * j]) + bfl(a1.s8[2 * j])) * inv,
                              (bfl(a0.s8[2 * j + 1]) + bfl(a1.s8[2 * j + 1])) * inv);
            *(bf16x8*)(lA + r * 72 + jp * 8) = o.v;
            *(bf16x8*)(lB + r * 72 + jp * 8) = vw[i];
        }
        __syncthreads();
        if (kk < 7) {
            int k0 = (kk + 1) * 64;
#pragma unroll
            for (int i = 0; i < 2; ++i) {
                int s = i * 256 + t;
                int r = s >> 3, jp = s & 7;
                va0[i] = ld8(Oh + (size_t)(m0 + r) * 512 + k0 + jp * 8);
                va1[i] = ld8(Oh + (size_t)(m0 + r + 4096) * 512 + k0 + jp * 8);
                l0[i] = Lsum[(bq_ * 8 + kk + 1) * 2048 + qq0 + r];
                l1[i] = Lsum[((2 + bq_) * 8 + kk + 1) * 2048 + qq0 + r];
                vw[i] = ld8(W + (size_t)(n0 + r) * 512 + k0 + jp * 8);
            }
        }

        bf16x8 af[2][2], bfrag[2][2];
#pragma unroll
        for (int ks = 0; ks < 2; ++ks) {
#pragma unroll
            for (int mt = 0; mt < 2; ++mt)
                af[mt][ks] = ld8(lA + (wm + mt * 16 + fr) * 72 + (ks * 4 + quad) * 8);
#pragma unroll
            for (int nt = 0; nt < 2; ++nt)
                bfrag[nt][ks] = ld8(lB + (wn + nt * 16 + fr) * 72 + (ks * 4 + quad) * 8);
        }
#pragma unroll
        for (int ks = 0; ks < 2; ++ks)
#pragma unroll
            for (int mt = 0; mt < 2; ++mt)
#pragma unroll
                for (int nt = 0; nt < 2; ++nt)
                    acc[mt][nt] = __builtin_amdgcn_mfma_f32_16x16x32_bf16(
                        af[mt][ks], bfrag[nt][ks], acc[mt][nt], 0, 0, 0);
    }

#pragma unroll
    for (int nt = 0; nt < 2; ++nt) {
        int n = n0 + wn + nt * 16 + fr;
        float bb = bias[n];
#pragma unroll
        for (int mt = 0; mt < 2; ++mt) {
            int mb = m0 + wm + mt * 16 + quad * 4;
#pragma unroll
            for (int r = 0; r < 4; ++r)
                dst[(size_t)(mb + r) * 512 + n] = acc[mt][nt][r] + bb;
        }
    }
}

// ---------------------------------------------------------------------------
// Flash attention (v7 config, session best): swapped QK^T, P in registers,
// VALU lsum, bf16 partial epilogue. grid (32,8,4) split-2; 4 waves x 16 q;
// LDS 32KB -> 4 blocks/CU = 16 waves/CU.
// ---------------------------------------------------------------------------
__global__ __launch_bounds__(256, 4)
void attn_kernel(const ushort_t* __restrict__ Q, const ushort_t* __restrict__ K,
                 const ushort_t* __restrict__ Vt, ushort_t* __restrict__ Opart,
                 float* __restrict__ Lsum)
{
    __shared__ ushort_t lK[128 * 64];
    __shared__ ushort_t lV[64 * 128];

    const int b = blockIdx.z >> 1, half = blockIdx.z & 1;
    const int h = blockIdx.y;
    const int q0 = blockIdx.x * 64;
    const int kvbase = half * 1024;
    const int t = threadIdx.x;
    const int lane = t & 63, w = t >> 6;
    const int wq = w * 16;
    const int fr = lane & 15, quad = lane >> 4;
    const int fr7 = fr & 7;

    bf16x8 aq[2];
    {
        const ushort_t* qp = Q + (size_t)(b * 2048 + q0 + wq + fr) * 512 + h * 64 + quad * 8;
        aq[0] = ld8(qp);
        aq[1] = ld8(qp + 32);
    }

    const int krl = w * 32 + (lane >> 3);
    const ushort_t* kg = K + (size_t)(b * 2048 + kvbase + krl) * 512 + h * 64
                           + (lane & 7) * 8;
    ushort_t* lk_wr = lK + krl * 64 + (((lane & 7) ^ (krl & 7)) << 3);

    const int vrl = w * 4 + (lane >> 4);
    const ushort_t* vbase = Vt + (size_t)((b * 8 + h) * 64 + vrl) * 2048 + kvbase
                              + (((lane & 15) ^ (vrl & 7)) << 3);

    const ushort_t* kr0 = lK + fr * 64 + ((quad ^ fr7) << 3);
    const ushort_t* kr1 = lK + fr * 64 + (((4 + quad) ^ fr7) << 3);
    const ushort_t* vr0 = lV + fr * 128 + (((0 * 4 + quad) ^ fr7) << 3);
    const ushort_t* vr1 = lV + fr * 128 + (((1 * 4 + quad) ^ fr7) << 3);
    const ushort_t* vr2 = lV + fr * 128 + (((2 * 4 + quad) ^ fr7) << 3);
    const ushort_t* vr3 = lV + fr * 128 + (((3 * 4 + quad) ^ fr7) << 3);
    const ushort_t* vr[4] = { vr0, vr1, vr2, vr3 };

    bf16x8 kreg[4];
#pragma unroll
    for (int i = 0; i < 4; ++i)
        kreg[i] = ld8(kg + (size_t)(i * 8) * 512);
#pragma unroll
    for (int i = 0; i < 4; ++i)
        *(bf16x8*)(lk_wr + i * 8 * 64) = kreg[i];
    __syncthreads();

    f32x4 oacc[4] = {};
    float lsum = 0.f;

    for (int tt = 0; tt < 8; ++tt) {
        const int kv = tt << 7;

#pragma unroll
        for (int i = 0; i < 4; ++i)
            gload_lds16(vbase + kv + (size_t)(i * 16) * 2048, lV + (i * 16 + w * 4) * 128);
        __builtin_amdgcn_sched_barrier(0);
        if (tt < 7) {
#pragma unroll
            for (int i = 0; i < 4; ++i)
                kreg[i] = ld8(kg + (size_t)(kv + 128 + i * 8) * 512);
        }
        __builtin_amdgcn_sched_barrier(0);

        f32x4 sc[8] = {};
        __builtin_amdgcn_s_setprio(1);
#pragma unroll
        for (int nt = 0; nt < 8; ++nt) {
            bf16x8 kb = ld8(kr0 + nt * 16 * 64);
            sc[nt] = __builtin_amdgcn_mfma_f32_16x16x32_bf16(kb, aq[0], sc[nt], 0, 0, 0);
        }
#pragma unroll
        for (int nt = 0; nt < 8; ++nt) {
            bf16x8 kb = ld8(kr1 + nt * 16 * 64);
            sc[nt] = __builtin_amdgcn_mfma_f32_16x16x32_bf16(kb, aq[1], sc[nt], 0, 0, 0);
        }
        __builtin_amdgcn_s_setprio(0);

        if (tt < 7) asm volatile("s_waitcnt vmcnt(4)" ::: "memory");
        else        asm volatile("s_waitcnt vmcnt(0)" ::: "memory");
        __builtin_amdgcn_s_barrier();
        __builtin_amdgcn_sched_barrier(0);

        __builtin_amdgcn_s_setprio(1);
#pragma unroll
        for (int ks = 0; ks < 4; ++ks) {
            float p0[4], p1[4];
#pragma unroll
            for (int r = 0; r < 4; ++r) p0[r] = exp2f(sc[2 * ks][r]);
#pragma unroll
            for (int r = 0; r < 4; ++r) p1[r] = exp2f(sc[2 * ks + 1][r]);
            lsum += ((p0[0] + p0[1]) + (p0[2] + p0[3]))
                  + ((p1[0] + p1[1]) + (p1[2] + p1[3]));
            union { unsigned u[4]; bf16x8 v; } pa;
            pa.u[0] = cvt2(p0[0], p0[1]); pa.u[1] = cvt2(p0[2], p0[3]);
            pa.u[2] = cvt2(p1[0], p1[1]); pa.u[3] = cvt2(p1[2], p1[3]);
#pragma unroll
            for (int nt = 0; nt < 4; ++nt) {
                bf16x8 vb = ld8(vr[ks] + nt * 16 * 128);
                oacc[nt] = __builtin_amdgcn_mfma_f32_16x16x32_bf16(pa.v, vb, oacc[nt], 0, 0, 0);
            }
            if (ks == 0 && tt < 7) {
#pragma unroll
                for (int i = 0; i < 4; ++i)
                    *(bf16x8*)(lk_wr + i * 8 * 64) = kreg[i];
            }
        }
        __builtin_amdgcn_s_setprio(0);
        __syncthreads();
    }

    float rs = lsum;
    rs += __shfl_xor(rs, 16, 64);
    rs += __shfl_xor(rs, 32, 64);
#pragma unroll
    for (int r = 0; r < 4; ++r) {
        int qrow = q0 + wq + quad * 4 + r;
        ushort_t* od = Opart + ((size_t)(half * 2 + b) * 2048 + qrow) * 512 + h * 64;
#pragma unroll
        for (int nt = 0; nt < 4; ++nt)
            od[nt * 16 + fr] = f2bf(oacc[nt][r]);
    }
    if (lane < 16)
        Lsum[((half * 2 + b) * 8 + h) * 2048 + q0 + wq + lane] = rs;
}

extern "C" void kernel_launch(void* const* d_in, const int* in_sizes, int n_in,
                              void* d_out, int out_size, void* d_ws, size_t ws_size,
                              hipStream_t stream) {
    const float* x   = (const float*)d_in[0];
    const float* Qe  = (const float*)d_in[1];
    const float* Ke  = (const float*)d_in[2];
    // d_in[3..6] scalars unused (drofe_fn is None in reference)
    const float* Wq  = (const float*)d_in[7];
    const float* bq  = (const float*)d_in[8];
    const float* Wk  = (const float*)d_in[9];
    const float* bk  = (const float*)d_in[10];
    const float* Wv  = (const float*)d_in[11];
    const float* bv  = (const float*)d_in[12];
    const float* Wo  = (const float*)d_in[13];
    const float* bo  = (const float*)d_in[14];

    const size_t NTOK = 2 * 2048;
    const size_t ACT = NTOK * 512;              // 2M elements

    ushort_t* p = (ushort_t*)d_ws;
    ushort_t* Wbf = p; p += (size_t)4 << 18;    // Wq|Wk|Wv|Wo bf16 (2 MB)
    ushort_t* Qws = p; p += ACT;                // [B,S,512] bf16, pre-scaled by C1
    ushort_t* Kws = p; p += ACT;                // [B,S,512] bf16
    ushort_t* Vt  = p; p += ACT;                // [B,H,64,S] bf16, rho-permuted
    ushort_t* OpH = p; p += 2 * ACT;            // [2,B,S,512] bf16 partials (8 MB)
    float* Lsum  = (float*)p;                   // [2,B,H,S] f32 (256 KB)

    cast_w_kernel<<<dim3(512), 256, 0, stream>>>(Wq, Wk, Wv, Wo, Wbf);
    proj_qkv_kernel<<<dim3(4, 64, 3), 256, 0, stream>>>(Qe, Ke, x, Wbf, bq, bk, bv,
                                                        Qws, Kws, Vt);
    attn_kernel<<<dim3(32, 8, 4), 256, 0, stream>>>(Qws, Kws, Vt, OpH, Lsum);
    gemm_o_kernel<<<dim3(8, 64), 256, 0, stream>>>(OpH, Lsum, Wbf + ((size_t)3 << 18),
                                                   bo, (float*)d_out);
}

// Round 12
// 149.602 us; speedup vs baseline: 1.0678x; 1.0678x over previous
//
#include <hip/hip_runtime.h>
#include <hip/hip_bf16.h>

typedef unsigned short ushort_t;
typedef __attribute__((ext_vector_type(8))) short bf16x8;
typedef __attribute__((ext_vector_type(4))) float f32x4;

__device__ __forceinline__ ushort_t f2bf(float f) {
    union { float f; unsigned u; } v; v.f = f;
    unsigned r = v.u + 0x7FFF + ((v.u >> 16) & 1);
    return (ushort_t)(r >> 16);
}
__device__ __forceinline__ float bfl(ushort_t u) {
    union { unsigned u; float f; } v; v.u = (unsigned)u << 16; return v.f;
}
__device__ __forceinline__ bf16x8 ld8(const ushort_t* p) { return *(const bf16x8*)p; }

__device__ __forceinline__ unsigned cvt2(float x, float y) {
    __hip_bfloat162 h = __float22bfloat162_rn(make_float2(x, y));
    unsigned r; __builtin_memcpy(&r, &h, 4); return r;
}
__device__ __forceinline__ bf16x8 pack8f(float4 a, float4 b) {
    union { unsigned u[4]; bf16x8 v; } o;
    o.u[0] = cvt2(a.x, a.y); o.u[1] = cvt2(a.z, a.w);
    o.u[2] = cvt2(b.x, b.y); o.u[3] = cvt2(b.z, b.w);
    return o.v;
}

// async global->LDS, 16B per lane; LDS dest = wave-uniform base + lane*16
__device__ __forceinline__ void gload_lds16(const ushort_t* g, ushort_t* l) {
    __builtin_amdgcn_global_load_lds(
        (const __attribute__((address_space(1))) void*)g,
        (__attribute__((address_space(3))) void*)l, 16, 0, 0);
}

// ---------------------------------------------------------------------------
// Cast pass: Qe|Ke|x -> Ab (3 x 2^21 bf16), Wq|Wk|Wv|Wo -> Wb (4 x 2^18 bf16).
// Streaming, no inter-block reuse -> no swizzle (T1 null on streaming ops).
// ---------------------------------------------------------------------------
__global__ __launch_bounds__(256)
void cast_kernel(const float* __restrict__ Qe, const float* __restrict__ Ke,
                 const float* __restrict__ x,  const float* __restrict__ Wq,
                 const float* __restrict__ Wk, const float* __restrict__ Wv,
                 const float* __restrict__ Wo,
                 ushort_t* __restrict__ Ab, ushort_t* __restrict__ Wb)
{
    const unsigned i8 = (blockIdx.x * 256u + threadIdx.x) * 8u;
    const float* src; ushort_t* dst;
    if (i8 < (3u << 21)) {
        unsigned a = i8 >> 21, off = i8 & ((1u << 21) - 1);
        src = (a == 0 ? Qe : a == 1 ? Ke : x) + off;
        dst = Ab + i8;
    } else {
        unsigned j = i8 - (3u << 21);
        unsigned a = j >> 18, off = j & ((1u << 18) - 1);
        src = (a == 0 ? Wq : a == 1 ? Wk : a == 2 ? Wv : Wo) + off;
        dst = Wb + j;
    }
    *(bf16x8*)dst = pack8f(*(const float4*)src, *(const float4*)(src + 4));
}

// ---------------------------------------------------------------------------
// Fused QKV projection (v10 datapath + XCD swizzle): 64x128 tile,
// grid (4, 64, 3) = 768 = 3 x 256 blocks, 3 blocks/CU, 48 KB LDS dbuf,
// bf16 inputs, global_load_lds DMA with XOR chunk-swizzle, vmcnt(0)+barrier.
// XCD swizzle (bijective, 768%8==0, q=96): the 4 n-blocks sharing an A
// row-panel become co-resident on one XCD -> A panel fetched ~once from HBM.
// z=0: Q*C1; z=1: K; z=2: V^T rho-permuted via LDS-transpose epilogue.
// ---------------------------------------------------------------------------
__global__ __launch_bounds__(256, 3)
void proj_qkv_kernel(const ushort_t* __restrict__ Ab, const ushort_t* __restrict__ Wb,
                     const float* __restrict__ bq, const float* __restrict__ bk,
                     const float* __restrict__ bv,
                     ushort_t* __restrict__ Qo, ushort_t* __restrict__ Ko,
                     ushort_t* __restrict__ Vt)
{
    __shared__ ushort_t smem[2 * 12288];   // 48 KB: [buf][A 64x64 | W 128x64]

    // XCD-aware bijective remap: hw linear -> logical (x fastest)
    const unsigned nlin = blockIdx.x + (blockIdx.y << 2) + (blockIdx.z << 8);
    const unsigned lg = (nlin & 7) * 96 + (nlin >> 3);
    const int bx = lg & 3, by = (lg >> 2) & 63, z = lg >> 8;

    const ushort_t* A = Ab + ((size_t)z << 21);
    const ushort_t* W = Wb + ((size_t)z << 18);
    const float* bias = (z == 0) ? bq : (z == 1) ? bk : bv;

    const int m0 = by * 64, n0 = bx * 128;
    const int t = threadIdx.x;
    const int lane = t & 63, wave = t >> 6;
    const int wm = (wave & 1) * 32, wn = (wave >> 1) * 64;
    const int fr = lane & 15, quad = lane >> 4;
    const int fr7 = fr & 7;

    // A DMA: wave covers rows wave*16 + i*8 + (lane>>3), i=0..1
    const int arl = wave * 16 + (lane >> 3);
    const ushort_t* ag = A + (size_t)(m0 + arl) * 512 + (((lane & 7) ^ (arl & 7)) << 3);
    const int dbA = wave * 16 * 64;
    // W DMA: wave covers rows wave*32 + i*8 + (lane>>3), i=0..3
    const int wrl = wave * 32 + (lane >> 3);
    const ushort_t* wg = W + (size_t)(n0 + wrl) * 512 + (((lane & 7) ^ (wrl & 7)) << 3);
    const int dbW = 4096 + wave * 32 * 64;

    f32x4 acc[2][4] = {};

    // prologue: stage k-tile 0 into buf 0
#pragma unroll
    for (int i = 0; i < 2; ++i)
        gload_lds16(ag + (size_t)(i * 8) * 512, smem + dbA + i * 512);
#pragma unroll
    for (int i = 0; i < 4; ++i)
        gload_lds16(wg + (size_t)(i * 8) * 512, smem + dbW + i * 512);
    __syncthreads();

    for (int kk = 0; kk < 8; ++kk) {
        ushort_t* cur = smem + (kk & 1) * 12288;
        ushort_t* nxt = smem + ((kk & 1) ^ 1) * 12288;
        if (kk < 7) {
            int ko = (kk + 1) * 64;
#pragma unroll
            for (int i = 0; i < 2; ++i)
                gload_lds16(ag + ko + (size_t)(i * 8) * 512, nxt + dbA + i * 512);
#pragma unroll
            for (int i = 0; i < 4; ++i)
                gload_lds16(wg + ko + (size_t)(i * 8) * 512, nxt + dbW + i * 512);
        }

#pragma unroll
        for (int ks = 0; ks < 2; ++ks) {
            bf16x8 af[2], bfr[4];
#pragma unroll
            for (int mt = 0; mt < 2; ++mt)
                af[mt] = ld8(cur + (wm + mt * 16 + fr) * 64 + (((ks * 4 + quad) ^ fr7) << 3));
#pragma unroll
            for (int nt = 0; nt < 4; ++nt)
                bfr[nt] = ld8(cur + 4096 + (wn + nt * 16 + fr) * 64 + (((ks * 4 + quad) ^ fr7) << 3));
#pragma unroll
            for (int mt = 0; mt < 2; ++mt)
#pragma unroll
                for (int nt = 0; nt < 4; ++nt)
                    acc[mt][nt] = __builtin_amdgcn_mfma_f32_16x16x32_bf16(
                        af[mt], bfr[nt], acc[mt][nt], 0, 0, 0);
        }
        asm volatile("s_waitcnt vmcnt(0)" ::: "memory");
        __builtin_amdgcn_s_barrier();
        __builtin_amdgcn_sched_barrier(0);
    }

    const float C1 = 0.125f * 1.44269504088896340736f;
    if (z != 2) {
        ushort_t* dst = (z == 0) ? Qo : Ko;
#pragma unroll
        for (int nt = 0; nt < 4; ++nt) {
            int n = n0 + wn + nt * 16 + fr;
            float bb = bias[n];
#pragma unroll
            for (int mt = 0; mt < 2; ++mt) {
                int mb = m0 + wm + mt * 16 + quad * 4;
                if (z == 0) {
#pragma unroll
                    for (int r = 0; r < 4; ++r)
                        dst[(size_t)(mb + r) * 512 + n] = f2bf((acc[mt][nt][r] + bb) * C1);
                } else {
#pragma unroll
                    for (int r = 0; r < 4; ++r)
                        dst[(size_t)(mb + r) * 512 + n] = f2bf(acc[mt][nt][r] + bb);
                }
            }
        }
    } else {
        // V^T epilogue: rho-scatter (local 64-token form) then b128 stores.
        ushort_t* lT = smem;              // [nl 0..127][sg 0..63], stride 72
#pragma unroll
        for (int nt = 0; nt < 4; ++nt) {
            int nl = wn + nt * 16 + fr;
            float bb = bias[n0 + nl];
#pragma unroll
            for (int mt = 0; mt < 2; ++mt) {
                int tm = wm + mt * 16 + quad * 4;
#pragma unroll
                for (int r = 0; r < 4; ++r) {
                    int tl = tm + r;     // 0..63 local token
                    int sg = (tl & 32) + ((tl & 12) << 1) + ((tl >> 4 & 1) << 2) + (tl & 3);
                    lT[nl * 72 + sg] = f2bf(acc[mt][nt][r] + bb);
                }
            }
        }
        __syncthreads();
        const int bidx = m0 >> 11, m0t = m0 & 2047;
#pragma unroll
        for (int i = 0; i < 4; ++i) {
            int s = i * 256 + t;
            int row = s >> 3, c = s & 7;     // row 0..127, chunk 0..7
            int n = n0 + row;
            int h = n >> 6, d = n & 63;
            bf16x8 v = ld8(lT + row * 72 + c * 8);
            *(bf16x8*)(Vt + ((size_t)((bidx * 8 + h) * 64 + d)) * 2048 + m0t + c * 8) = v;
        }
    }
}

// ---------------------------------------------------------------------------
// Fused O-projection (+ XCD swizzle, q=64): the 8 n-blocks sharing an A
// m-panel co-locate on one XCD -> A (bf16 partials) HBM traffic ~/8.
// A = bf16((O0+O1) * 1/(l0+l1)); W bf16. 64x64 tile, grid (8,64), BK=64.
// ---------------------------------------------------------------------------
__global__ __launch_bounds__(256, 2)
void gemm_o_kernel(const ushort_t* __restrict__ Oh, const float* __restrict__ Lsum,
                   const ushort_t* __restrict__ W, const float* __restrict__ bias,
                   float* __restrict__ dst)
{
    __shared__ ushort_t lA[64 * 72];
    __shared__ ushort_t lB[64 * 72];

    const unsigned nlin = blockIdx.x + (blockIdx.y << 3);
    const unsigned lg = (nlin & 7) * 64 + (nlin >> 3);
    const int m0 = (lg >> 3) * 64, n0 = (lg & 7) * 64;

    const int t = threadIdx.x;
    const int lane = t & 63, wave = t >> 6;
    const int wm = (wave & 1) * 32, wn = (wave >> 1) * 32;
    const int fr = lane & 15, quad = lane >> 4;
    const int bq_ = m0 >> 11, qq0 = m0 & 2047;

    f32x4 acc[2][2] = {};
    bf16x8 va0[2], va1[2], vw[2];
    float l0[2], l1[2];

#pragma unroll
    for (int i = 0; i < 2; ++i) {
        int s = i * 256 + t;
        int r = s >> 3, jp = s & 7;
        va0[i] = ld8(Oh + (size_t)(m0 + r) * 512 + jp * 8);
        va1[i] = ld8(Oh + (size_t)(m0 + r + 4096) * 512 + jp * 8);
        l0[i] = Lsum[(bq_ * 8 + 0) * 2048 + qq0 + r];
        l1[i] = Lsum[((2 + bq_) * 8 + 0) * 2048 + qq0 + r];
        vw[i] = ld8(W + (size_t)(n0 + r) * 512 + jp * 8);
    }

    for (int kk = 0; kk < 8; ++kk) {
        if (kk) __syncthreads();
#pragma unroll
        for (int i = 0; i < 2; ++i) {
            int s = i * 256 + t;
            int r = s >> 3, jp = s & 7;
            float inv = 1.f / (l0[i] + l1[i]);
            union { bf16x8 v; ushort_t s8[8]; } a0, a1;
            a0.v = va0[i]; a1.v = va1[i];
            union { unsigned u[4]; bf16x8 v; } o;
#pragma unroll
            for (int j = 0; j < 4; ++j)
                o.u[j] = cvt2((bfl(a0.s8[2 * j]) + bfl(a1.s8[2 * j])) * inv,
                              (bfl(a0.s8[2 * j + 1]) + bfl(a1.s8[2 * j + 1])) * inv);
            *(bf16x8*)(lA + r * 72 + jp * 8) = o.v;
            *(bf16x8*)(lB + r * 72 + jp * 8) = vw[i];
        }
        __syncthreads();
        if (kk < 7) {
            int k0 = (kk + 1) * 64;
#pragma unroll
            for (int i = 0; i < 2; ++i) {
                int s = i * 256 + t;
                int r = s >> 3, jp = s & 7;
                va0[i] = ld8(Oh + (size_t)(m0 + r) * 512 + k0 + jp * 8);
                va1[i] = ld8(Oh + (size_t)(m0 + r + 4096) * 512 + k0 + jp * 8);
                l0[i] = Lsum[(bq_ * 8 + kk + 1) * 2048 + qq0 + r];
                l1[i] = Lsum[((2 + bq_) * 8 + kk + 1) * 2048 + qq0 + r];
                vw[i] = ld8(W + (size_t)(n0 + r) * 512 + k0 + jp * 8);
            }
        }

        bf16x8 af[2][2], bfrag[2][2];
#pragma unroll
        for (int ks = 0; ks < 2; ++ks) {
#pragma unroll
            for (int mt = 0; mt < 2; ++mt)
                af[mt][ks] = ld8(lA + (wm + mt * 16 + fr) * 72 + (ks * 4 + quad) * 8);
#pragma unroll
            for (int nt = 0; nt < 2; ++nt)
                bfrag[nt][ks] = ld8(lB + (wn + nt * 16 + fr) * 72 + (ks * 4 + quad) * 8);
        }
#pragma unroll
        for (int ks = 0; ks < 2; ++ks)
#pragma unroll
            for (int mt = 0; mt < 2; ++mt)
#pragma unroll
                for (int nt = 0; nt < 2; ++nt)
                    acc[mt][nt] = __builtin_amdgcn_mfma_f32_16x16x32_bf16(
                        af[mt][ks], bfrag[nt][ks], acc[mt][nt], 0, 0, 0);
    }

#pragma unroll
    for (int nt = 0; nt < 2; ++nt) {
        int n = n0 + wn + nt * 16 + fr;
        float bb = bias[n];
#pragma unroll
        for (int mt = 0; mt < 2; ++mt) {
            int mb = m0 + wm + mt * 16 + quad * 4;
#pragma unroll
            for (int r = 0; r < 4; ++r)
                dst[(size_t)(mb + r) * 512 + n] = acc[mt][nt][r] + bb;
        }
    }
}

// ---------------------------------------------------------------------------
// Flash attention (v7 datapath + XCD swizzle, q=128): the 32 q-blocks
// sharing a (b,h,half) K/V panel co-locate on one XCD -> K/V L2-shared.
// Swapped QK^T, P in registers, VALU lsum, bf16 partial epilogue.
// grid (32,8,4) split-2; 4 waves x 16 q; LDS 32KB -> 4 blocks/CU.
// ---------------------------------------------------------------------------
__global__ __launch_bounds__(256, 4)
void attn_kernel(const ushort_t* __restrict__ Q, const ushort_t* __restrict__ K,
                 const ushort_t* __restrict__ Vt, ushort_t* __restrict__ Opart,
                 float* __restrict__ Lsum)
{
    __shared__ ushort_t lK[128 * 64];
    __shared__ ushort_t lV[64 * 128];

    const unsigned nlin = blockIdx.x + (blockIdx.y << 5) + (blockIdx.z << 8);
    const unsigned lg = (nlin & 7) * 128 + (nlin >> 3);
    const int bz = lg >> 8;                 // 0..3
    const int b = bz >> 1, half = bz & 1;
    const int h = (lg >> 5) & 7;
    const int q0 = (lg & 31) * 64;

    const int kvbase = half * 1024;
    const int t = threadIdx.x;
    const int lane = t & 63, w = t >> 6;
    const int wq = w * 16;
    const int fr = lane & 15, quad = lane >> 4;
    const int fr7 = fr & 7;

    bf16x8 aq[2];
    {
        const ushort_t* qp = Q + (size_t)(b * 2048 + q0 + wq + fr) * 512 + h * 64 + quad * 8;
        aq[0] = ld8(qp);
        aq[1] = ld8(qp + 32);
    }

    const int krl = w * 32 + (lane >> 3);
    const ushort_t* kg = K + (size_t)(b * 2048 + kvbase + krl) * 512 + h * 64
                           + (lane & 7) * 8;
    ushort_t* lk_wr = lK + krl * 64 + (((lane & 7) ^ (krl & 7)) << 3);

    const int vrl = w * 4 + (lane >> 4);
    const ushort_t* vbase = Vt + (size_t)((b * 8 + h) * 64 + vrl) * 2048 + kvbase
                              + (((lane & 15) ^ (vrl & 7)) << 3);

    const ushort_t* kr0 = lK + fr * 64 + ((quad ^ fr7) << 3);
    const ushort_t* kr1 = lK + fr * 64 + (((4 + quad) ^ fr7) << 3);
    const ushort_t* vr0 = lV + fr * 128 + (((0 * 4 + quad) ^ fr7) << 3);
    const ushort_t* vr1 = lV + fr * 128 + (((1 * 4 + quad) ^ fr7) << 3);
    const ushort_t* vr2 = lV + fr * 128 + (((2 * 4 + quad) ^ fr7) << 3);
    const ushort_t* vr3 = lV + fr * 128 + (((3 * 4 + quad) ^ fr7) << 3);
    const ushort_t* vr[4] = { vr0, vr1, vr2, vr3 };

    bf16x8 kreg[4];
#pragma unroll
    for (int i = 0; i < 4; ++i)
        kreg[i] = ld8(kg + (size_t)(i * 8) * 512);
#pragma unroll
    for (int i = 0; i < 4; ++i)
        *(bf16x8*)(lk_wr + i * 8 * 64) = kreg[i];
    __syncthreads();

    f32x4 oacc[4] = {};
    float lsum = 0.f;

    for (int tt = 0; tt < 8; ++tt) {
        const int kv = tt << 7;

#pragma unroll
        for (int i = 0; i < 4; ++i)
            gload_lds16(vbase + kv + (size_t)(i * 16) * 2048, lV + (i * 16 + w * 4) * 128);
        __builtin_amdgcn_sched_barrier(0);
        if (tt < 7) {
#pragma unroll
            for (int i = 0; i < 4; ++i)
                kreg[i] = ld8(kg + (size_t)(kv + 128 + i * 8) * 512);
        }
        __builtin_amdgcn_sched_barrier(0);

        f32x4 sc[8] = {};
        __builtin_amdgcn_s_setprio(1);
#pragma unroll
        for (int nt = 0; nt < 8; ++nt) {
            bf16x8 kb = ld8(kr0 + nt * 16 * 64);
            sc[nt] = __builtin_amdgcn_mfma_f32_16x16x32_bf16(kb, aq[0], sc[nt], 0, 0, 0);
        }
#pragma unroll
        for (int nt = 0; nt < 8; ++nt) {
            bf16x8 kb = ld8(kr1 + nt * 16 * 64);
            sc[nt] = __builtin_amdgcn_mfma_f32_16x16x32_bf16(kb, aq[1], sc[nt], 0, 0, 0);
        }
        __builtin_amdgcn_s_setprio(0);

        if (tt < 7) asm volatile("s_waitcnt vmcnt(4)" ::: "memory");
        else        asm volatile("s_waitcnt vmcnt(0)" ::: "memory");
        __builtin_amdgcn_s_barrier();
        __builtin_amdgcn_sched_barrier(0);

        __builtin_amdgcn_s_setprio(1);
#pragma unroll
        for (int ks = 0; ks < 4; ++ks) {
            float p0[4], p1[4];
#pragma unroll
            for (int r = 0; r < 4; ++r) p0[r] = exp2f(sc[2 * ks][r]);
#pragma unroll
            for (int r = 0; r < 4; ++r) p1[r] = exp2f(sc[2 * ks + 1][r]);
            lsum += ((p0[0] + p0[1]) + (p0[2] + p0[3]))
                  + ((p1[0] + p1[1]) + (p1[2] + p1[3]));
            union { unsigned u[4]; bf16x8 v; } pa;
            pa.u[0] = cvt2(p0[0], p0[1]); pa.u[1] = cvt2(p0[2], p0[3]);
            pa.u[2] = cvt2(p1[0], p1[1]); pa.u[3] = cvt2(p1[2], p1[3]);
#pragma unroll
            for (int nt = 0; nt < 4; ++nt) {
                bf16x8 vb = ld8(vr[ks] + nt * 16 * 128);
                oacc[nt] = __builtin_amdgcn_mfma_f32_16x16x32_bf16(pa.v, vb, oacc[nt], 0, 0, 0);
            }
            if (ks == 0 && tt < 7) {
#pragma unroll
                for (int i = 0; i < 4; ++i)
                    *(bf16x8*)(lk_wr + i * 8 * 64) = kreg[i];
            }
        }
        __builtin_amdgcn_s_setprio(0);
        __syncthreads();
    }

    float rs = lsum;
    rs += __shfl_xor(rs, 16, 64);
    rs += __shfl_xor(rs, 32, 64);
#pragma unroll
    for (int r = 0; r < 4; ++r) {
        int qrow = q0 + wq + quad * 4 + r;
        ushort_t* od = Opart + ((size_t)(half * 2 + b) * 2048 + qrow) * 512 + h * 64;
#pragma unroll
        for (int nt = 0; nt < 4; ++nt)
            od[nt * 16 + fr] = f2bf(oacc[nt][r]);
    }
    if (lane < 16)
        Lsum[((half * 2 + b) * 8 + h) * 2048 + q0 + wq + lane] = rs;
}

extern "C" void kernel_launch(void* const* d_in, const int* in_sizes, int n_in,
                              void* d_out, int out_size, void* d_ws, size_t ws_size,
                              hipStream_t stream) {
    const float* x   = (const float*)d_in[0];
    const float* Qe  = (const float*)d_in[1];
    const float* Ke  = (const float*)d_in[2];
    // d_in[3..6] scalars unused (drofe_fn is None in reference)
    const float* Wq  = (const float*)d_in[7];
    const float* bq  = (const float*)d_in[8];
    const float* Wk  = (const float*)d_in[9];
    const float* bk  = (const float*)d_in[10];
    const float* Wv  = (const float*)d_in[11];
    const float* bv  = (const float*)d_in[12];
    const float* Wo  = (const float*)d_in[13];
    const float* bo  = (const float*)d_in[14];

    const size_t NTOK = 2 * 2048;
    const size_t ACT = NTOK * 512;              // 2M elements

    ushort_t* p = (ushort_t*)d_ws;
    ushort_t* Abf = p; p += (size_t)3 << 21;    // Qe|Ke|x bf16 (12 MB)
    ushort_t* Wbf = p; p += (size_t)4 << 18;    // Wq|Wk|Wv|Wo bf16 (2 MB)
    ushort_t* Qws = p; p += ACT;                // [B,S,512] bf16, pre-scaled by C1
    ushort_t* Kws = p; p += ACT;                // [B,S,512] bf16
    ushort_t* Vt  = p; p += ACT;                // [B,H,64,S] bf16, rho-permuted
    ushort_t* OpH = p; p += 2 * ACT;            // [2,B,S,512] bf16 partials (8 MB)
    float* Lsum  = (float*)p;                   // [2,B,H,S] f32 (256 KB)

    cast_kernel<<<dim3(3584), 256, 0, stream>>>(Qe, Ke, x, Wq, Wk, Wv, Wo, Abf, Wbf);
    proj_qkv_kernel<<<dim3(4, 64, 3), 256, 0, stream>>>(Abf, Wbf, bq, bk, bv,
                                                        Qws, Kws, Vt);
    attn_kernel<<<dim3(32, 8, 4), 256, 0, stream>>>(Qws, Kws, Vt, OpH, Lsum);
    gemm_o_kernel<<<dim3(8, 64), 256, 0, stream>>>(OpH, Lsum, Wbf + ((size_t)3 << 18),
                                                   bo, (float*)d_out);
}